// Round 1
// baseline (2156.163 us; speedup 1.0000x reference)
//
#include <hip/hip_runtime.h>

#define EPSV 1e-5f

constexpr int B_ = 16, C_ = 256;
constexpr int OHW_ = 49 * 49;          // 2401
constexpr int NTOT = 256 * 16 * 16;    // 65536 (C*th*tw)
constexpr int GROUPS = 32, CPERG = 8;  // cross-corr channel split

// workspace layout (float offsets)
constexpr size_t OFF_S1 = 0;                               // 16*256*64*64
constexpr size_t SZ_S1  = (size_t)16 * 256 * 64 * 64;      // 16777216
constexpr size_t OFF_T2 = OFF_S1 + SZ_S1;                  // 16*256*16*16
constexpr size_t SZ_T2  = (size_t)16 * 256 * 16 * 16;      // 1048576
constexpr size_t OFF_Z  = OFF_T2 + SZ_T2;                  // 16*64*64
constexpr size_t OFF_Z2 = OFF_Z + 65536;
constexpr size_t OFF_CP = OFF_Z2 + 65536;                  // GROUPS*16*2401
constexpr size_t SZ_CP  = (size_t)GROUPS * 16 * OHW_;
constexpr size_t OFF_NCC = OFF_CP + SZ_CP;                 // 16*2401
constexpr size_t OFF_ST  = OFF_NCC + (size_t)16 * OHW_;    // stats block

// -------------------- conv3x3 (pad 1) + bias + per-channel sum/sumsq --------------------
template<int OCT, int H, int W>
__global__ __launch_bounds__(256)
void conv3x3_stats(const float* __restrict__ in, const float* __restrict__ wgt,
                   const float* __restrict__ bias, float* __restrict__ out,
                   float* __restrict__ csum, float* __restrict__ csq)
{
    constexpr int NY = 256 / OCT;       // y-groups
    constexpr int SLOTS = OCT / 16;     // y-slots per thread
    constexpr int TXN = W / 16, TYN = H / 16;
    constexpr int OCG = C_ / OCT;

    __shared__ float in_lds[8 * 18 * 20];   // 8 ic x 18 rows x pitch 20 (16B-aligned rows)
    __shared__ float w_lds[OCT * 73];       // stride 73 -> conflict-free
    __shared__ float red[512];

    int bid = blockIdx.x;
    int tx = bid % TXN; bid /= TXN;
    int ty = bid % TYN; bid /= TYN;
    int og = bid % OCG; bid /= OCG;
    int b  = bid;
    int tid = threadIdx.x;
    int oc_l = tid % OCT;
    int ys = tid / OCT;
    int x0 = tx * 16 - 1, y0 = ty * 16 - 1;
    int oc0 = og * OCT;

    float acc[SLOTS][16];
    float bv = bias[oc0 + oc_l];
    #pragma unroll
    for (int s = 0; s < SLOTS; ++s)
        #pragma unroll
        for (int x = 0; x < 16; ++x) acc[s][x] = bv;

    for (int ic0 = 0; ic0 < C_; ic0 += 8) {
        __syncthreads();
        // stage input patch (zero-padded)
        for (int idx = tid; idx < 8 * 18 * 18; idx += 256) {
            int icc = idx / 324; int rem = idx - icc * 324;
            int yy = rem / 18;   int xx = rem - yy * 18;
            int gy = y0 + yy, gx = x0 + xx;
            float v = 0.f;
            if (gy >= 0 && gy < H && gx >= 0 && gx < W)
                v = in[((b * C_ + ic0 + icc) * H + gy) * W + gx];
            in_lds[icc * 360 + yy * 20 + xx] = v;
        }
        // stage weights (coalesced), padded stride 73
        for (int idx = tid; idx < OCT * 72; idx += 256) {
            int oc = idx / 72; int off = idx - oc * 72;
            w_lds[oc * 73 + off] = wgt[((oc0 + oc) * C_ + ic0 + off / 9) * 9 + (off % 9)];
        }
        __syncthreads();
        #pragma unroll 2
        for (int icc = 0; icc < 8; ++icc) {
            #pragma unroll
            for (int s = 0; s < SLOTS; ++s) {
                int y = ys + s * NY;
                #pragma unroll
                for (int ky = 0; ky < 3; ++ky) {
                    const float* row = &in_lds[icc * 360 + (y + ky) * 20];
                    float r[18];
                    #pragma unroll
                    for (int xx = 0; xx < 18; ++xx) r[xx] = row[xx];
                    float w0 = w_lds[oc_l * 73 + icc * 9 + ky * 3 + 0];
                    float w1 = w_lds[oc_l * 73 + icc * 9 + ky * 3 + 1];
                    float w2 = w_lds[oc_l * 73 + icc * 9 + ky * 3 + 2];
                    #pragma unroll
                    for (int x = 0; x < 16; ++x)
                        acc[s][x] += w0 * r[x] + w1 * r[x + 1] + w2 * r[x + 2];
                }
            }
        }
    }

    float ls = 0.f, lq = 0.f;
    #pragma unroll
    for (int s = 0; s < SLOTS; ++s) {
        int y = ty * 16 + ys + s * NY;
        float* orow = &out[((b * C_ + oc0 + oc_l) * H + y) * W + tx * 16];
        #pragma unroll
        for (int x = 0; x < 16; ++x) {
            float v = acc[s][x];
            ls += v; lq += v * v;
            orow[x] = v;
        }
    }
    red[tid] = ls; red[256 + tid] = lq;
    __syncthreads();
    if (ys == 0) {
        float ss = 0.f, qq = 0.f;
        #pragma unroll
        for (int n = 0; n < NY; ++n) { ss += red[oc_l + n * OCT]; qq += red[256 + oc_l + n * OCT]; }
        atomicAdd(&csum[oc0 + oc_l], ss);
        atomicAdd(&csq[oc0 + oc_l], qq);
    }
}

// -------------------- BN normalize in place (training stats from sums) --------------------
__global__ __launch_bounds__(256)
void bn_norm(float* __restrict__ x, const float* __restrict__ csum,
             const float* __restrict__ csq, const float* __restrict__ g,
             const float* __restrict__ be, int HW, int total4, float inv_cnt)
{
    int i = blockIdx.x * 256 + threadIdx.x;
    if (i >= total4) return;
    int c = ((i * 4) / HW) % C_;
    float m = csum[c] * inv_cnt;
    float v = csq[c] * inv_cnt - m * m;
    float sc = rsqrtf(v + EPSV) * g[c];
    float sh = be[c] - m * sc;
    float4 val = reinterpret_cast<float4*>(x)[i];
    val.x = val.x * sc + sh;
    val.y = val.y * sc + sh;
    val.z = val.z * sc + sh;
    val.w = val.w * sc + sh;
    reinterpret_cast<float4*>(x)[i] = val;
}

// -------------------- channel-summed planes of normalized s (and squares) --------------------
__global__ __launch_bounds__(256)
void zplane_kernel(const float* __restrict__ s1, float* __restrict__ z, float* __restrict__ z2)
{
    int i = blockIdx.x * 256 + threadIdx.x;  // 0..65535
    int b = i >> 12, p = i & 4095;
    const float* base = s1 + (size_t)b * C_ * 4096 + p;
    float s = 0.f, q = 0.f;
    for (int c = 0; c < C_; ++c) { float v = base[(size_t)c * 4096]; s += v; q += v * v; }
    z[i] = s; z2[i] = q;
}

// -------------------- block reduce helper --------------------
__device__ inline void blk_reduce2(float& a, float& q, int tid) {
    #pragma unroll
    for (int off = 32; off > 0; off >>= 1) {
        a += __shfl_down(a, off);
        q += __shfl_down(q, off);
    }
    __shared__ float ra[4], rq[4];
    if ((tid & 63) == 0) { ra[tid >> 6] = a; rq[tid >> 6] = q; }
    __syncthreads();
    if (tid == 0) { a = ra[0] + ra[1] + ra[2] + ra[3]; q = rq[0] + rq[1] + rq[2] + rq[3]; }
}

// -------------------- per-batch template stats (mean, unbiased std) --------------------
__global__ __launch_bounds__(256)
void tstat_kernel(const float* __restrict__ t2, float* __restrict__ tmean, float* __restrict__ ttstd)
{
    int b = blockIdx.x, tid = threadIdx.x;
    const float* p = t2 + (size_t)b * NTOT;
    float s = 0.f, q = 0.f;
    for (int i = tid; i < NTOT; i += 256) { float v = p[i]; s += v; q += v * v; }
    blk_reduce2(s, q, tid);
    if (tid == 0) {
        float m = s / (float)NTOT;
        tmean[b] = m;
        ttstd[b] = sqrtf(fmaxf(q - (float)NTOT * m * m, 0.f) / (float)(NTOT - 1));
    }
}

// -------------------- raw cross-correlation, channel-split partials --------------------
__global__ __launch_bounds__(256)
void cross_kernel(const float* __restrict__ s1, const float* __restrict__ t2,
                  float* __restrict__ cpart)
{
    __shared__ float spl[4096];
    __shared__ float tpl[256];
    int g = blockIdx.x & (GROUPS - 1);
    int b = blockIdx.x / GROUPS;
    int tid = threadIdx.x;

    float acc[10];
    #pragma unroll
    for (int k = 0; k < 10; ++k) acc[k] = 0.f;

    int io[10], jo[10];
    #pragma unroll
    for (int k = 0; k < 10; ++k) {
        int o = tid + k * 256;
        if (o >= OHW_) o = 0;
        io[k] = o / 49; jo[k] = o % 49;
    }

    for (int cc = 0; cc < CPERG; ++cc) {
        int c = g * CPERG + cc;
        __syncthreads();
        const float4* sp4 = reinterpret_cast<const float4*>(s1 + ((size_t)(b * C_ + c)) * 4096);
        float4* dst4 = reinterpret_cast<float4*>(spl);
        #pragma unroll
        for (int k = 0; k < 4; ++k) dst4[tid + k * 256] = sp4[tid + k * 256];
        tpl[tid] = t2[((size_t)(b * C_ + c)) * 256 + tid];
        __syncthreads();
        #pragma unroll 2
        for (int ty_ = 0; ty_ < 16; ++ty_) {
            float tr[16];
            #pragma unroll
            for (int tx_ = 0; tx_ < 16; ++tx_) tr[tx_] = tpl[ty_ * 16 + tx_];
            #pragma unroll
            for (int k = 0; k < 10; ++k) {
                const float* srow = &spl[(io[k] + ty_) * 64 + jo[k]];
                float a = acc[k];
                #pragma unroll
                for (int tx_ = 0; tx_ < 16; ++tx_) a += tr[tx_] * srow[tx_];
                acc[k] = a;
            }
        }
    }
    float* dst = cpart + ((size_t)(g * B_ + b)) * OHW_;
    #pragma unroll
    for (int k = 0; k < 9; ++k) dst[tid + k * 256] = acc[k];
    if (tid < OHW_ - 9 * 256) dst[tid + 9 * 256] = acc[9];
}

// -------------------- NCC assembly + global stats of ncc --------------------
__global__ __launch_bounds__(256)
void ncc_kernel(const float* __restrict__ cpart, const float* __restrict__ z,
                const float* __restrict__ z2, const float* __restrict__ tmean,
                const float* __restrict__ ttstd, float* __restrict__ ncc,
                float* __restrict__ s3)
{
    int idx = blockIdx.x * 256 + threadIdx.x;
    float val = 0.f;
    if (idx < B_ * OHW_) {
        int b = idx / OHW_, r = idx - b * OHW_;
        int i = r / 49, j = r - i * 49;
        float cr = 0.f;
        #pragma unroll 4
        for (int g = 0; g < GROUPS; ++g) cr += cpart[((size_t)(g * B_ + b)) * OHW_ + r];
        const float* zb  = z  + b * 4096;
        const float* z2b = z2 + b * 4096;
        float wsum = 0.f, wq = 0.f;
        for (int ty_ = 0; ty_ < 16; ++ty_) {
            const float* zr  = zb  + (i + ty_) * 64 + j;
            const float* z2r = z2b + (i + ty_) * 64 + j;
            #pragma unroll
            for (int tx_ = 0; tx_ < 16; ++tx_) { wsum += zr[tx_]; wq += z2r[tx_]; }
        }
        float crosst = cr - tmean[b] * wsum;
        float ssvar = fmaxf(wq - wsum * wsum * (1.f / 65536.f), 0.f) * (1.f / 65535.f);
        float ssstd = sqrtf(ssvar);
        val = crosst / (65536.f * ttstd[b] * ssstd);
        ncc[idx] = val;
    }
    float s = val, q = val * val;
    blk_reduce2(s, q, threadIdx.x);
    if (threadIdx.x == 0) { atomicAdd(&s3[0], s); atomicAdd(&s3[1], q); }
}

// -------------------- conv3 + BN3 + relu + conv4 (all scalar-channel) --------------------
__global__ __launch_bounds__(256)
void final_kernel(const float* __restrict__ ncc, const float* __restrict__ s3,
                  const float* __restrict__ w3, const float* __restrict__ b3,
                  const float* __restrict__ g3, const float* __restrict__ be3,
                  const float* __restrict__ w4, const float* __restrict__ b4,
                  float* __restrict__ out)
{
    int idx = blockIdx.x * 256 + threadIdx.x;
    if (idx >= B_ * OHW_) return;
    constexpr float M = (float)(B_ * OHW_);
    float mn = s3[0] / M;
    float vn = s3[1] / M - mn * mn;
    float W3 = w3[0], B3 = b3[0];
    float my = W3 * mn + B3;
    float vy = W3 * W3 * vn;
    float sc = rsqrtf(vy + EPSV) * g3[0];
    float y = (W3 * ncc[idx] + B3 - my) * sc + be3[0];
    float h = fmaxf(y, 0.f);
    int b = idx / OHW_, r = idx - b * OHW_;
    out[((size_t)(b * 2 + 0)) * OHW_ + r] = h * w4[0] + b4[0];
    out[((size_t)(b * 2 + 1)) * OHW_ + r] = h * w4[1] + b4[1];
}

extern "C" void kernel_launch(void* const* d_in, const int* in_sizes, int n_in,
                              void* d_out, int out_size, void* d_ws, size_t ws_size,
                              hipStream_t stream)
{
    const float* s   = (const float*)d_in[0];
    const float* t   = (const float*)d_in[1];
    const float* w1  = (const float*)d_in[2];
    const float* b1  = (const float*)d_in[3];
    const float* g1  = (const float*)d_in[4];
    const float* be1 = (const float*)d_in[5];
    const float* w2  = (const float*)d_in[6];
    const float* b2  = (const float*)d_in[7];
    const float* g2  = (const float*)d_in[8];
    const float* be2 = (const float*)d_in[9];
    const float* w3  = (const float*)d_in[10];
    const float* b3  = (const float*)d_in[11];
    const float* g3  = (const float*)d_in[12];
    const float* be3 = (const float*)d_in[13];
    const float* w4  = (const float*)d_in[14];
    const float* b4  = (const float*)d_in[15];

    float* ws = (float*)d_ws;
    float* S1 = ws + OFF_S1;
    float* T2 = ws + OFF_T2;
    float* Z  = ws + OFF_Z;
    float* Z2 = ws + OFF_Z2;
    float* CP = ws + OFF_CP;
    float* NC = ws + OFF_NCC;
    float* ST = ws + OFF_ST;
    float* CHS1 = ST + 0;
    float* CHQ1 = ST + 256;
    float* CHS2 = ST + 512;
    float* CHQ2 = ST + 768;
    float* S3   = ST + 1024;   // [2]
    float* TM   = ST + 1040;   // [16]
    float* TSD  = ST + 1056;   // [16]

    hipMemsetAsync(ST, 0, 1026 * sizeof(float), stream);

    conv3x3_stats<32, 64, 64><<<dim3(2048), dim3(256), 0, stream>>>(s, w1, b1, S1, CHS1, CHQ1);
    conv3x3_stats<16, 16, 16><<<dim3(256),  dim3(256), 0, stream>>>(t, w2, b2, T2, CHS2, CHQ2);
    bn_norm<<<dim3(16384), dim3(256), 0, stream>>>(S1, CHS1, CHQ1, g1, be1, 4096, 4194304, 1.f / 65536.f);
    bn_norm<<<dim3(1024),  dim3(256), 0, stream>>>(T2, CHS2, CHQ2, g2, be2, 256, 262144, 1.f / 4096.f);
    zplane_kernel<<<dim3(256), dim3(256), 0, stream>>>(S1, Z, Z2);
    tstat_kernel<<<dim3(16), dim3(256), 0, stream>>>(T2, TM, TSD);
    cross_kernel<<<dim3(16 * GROUPS), dim3(256), 0, stream>>>(S1, T2, CP);
    ncc_kernel<<<dim3(151), dim3(256), 0, stream>>>(CP, Z, Z2, TM, TSD, NC, S3);
    final_kernel<<<dim3(151), dim3(256), 0, stream>>>(NC, S3, w3, b3, g3, be3, w4, b4, (float*)d_out);
}

// Round 2
// 612.724 us; speedup vs baseline: 3.5190x; 3.5190x over previous
//
#include <hip/hip_runtime.h>
#include <hip/hip_bf16.h>

#define EPSV 1e-5f

constexpr int B_ = 16, C_ = 256;
constexpr int OHW_ = 49 * 49;          // 2401
constexpr int NTOT = 256 * 16 * 16;    // 65536
constexpr int GROUPS = 32, CPERG = 8;

typedef short bf16x8 __attribute__((ext_vector_type(8)));
typedef float f32x4 __attribute__((ext_vector_type(4)));

// ---------------- workspace layout ----------------
// floats
constexpr size_t OFF_S1 = 0;                               // 16*256*4096 f32
constexpr size_t SZ_S1  = (size_t)16 * 256 * 4096;
constexpr size_t OFF_T2 = OFF_S1 + SZ_S1;                  // 16*256*256 f32
constexpr size_t SZ_T2  = (size_t)16 * 256 * 256;
constexpr size_t OFF_ST = OFF_T2 + SZ_T2;                  // stats block (2048 f)
constexpr size_t OFF_C  = OFF_ST + 2048;                   // overlaid big region
// region C, byte offsets (bf16 staging, alive only through conv)
constexpr size_t SPC_BYTES = (size_t)16 * 66 * 66 * 256 * 2;   // 35,684,352
constexpr size_t TPC_BYTES = (size_t)16 * 18 * 18 * 256 * 2;   //  2,654,208
constexpr size_t WR_BYTES  = (size_t)9 * 256 * 256 * 2;        //  1,179,648
// region C overlay, float offsets (alive after conv)
constexpr size_t ZOFF  = 0;              // 65536
constexpr size_t Z2OFF = 65536;          // 65536
constexpr size_t CPOFF = 131072;         // 32*16*2401
constexpr size_t NCOFF = CPOFF + (size_t)GROUPS * 16 * OHW_;

// ---------------- async global->LDS 16B ----------------
__device__ __forceinline__ void gload_lds16(const void* g, void* l) {
    __builtin_amdgcn_global_load_lds((const __attribute__((address_space(1))) unsigned int*)g,
                                     (__attribute__((address_space(3))) unsigned int*)l,
                                     16, 0, 0);
}

// ---------------- pad + NCHW->NHWC + bf16 ----------------
template<int W>   // H == W, C=256; out [b][W+2][W+2][256], borders pre-zeroed
__global__ __launch_bounds__(256)
void pad_transpose(const float* __restrict__ in, __hip_bfloat16* __restrict__ outp)
{
    constexpr int PW = W + 2;
    __shared__ float tile[64][W + 1];
    int bid = blockIdx.x;
    int icg = bid & 3; bid >>= 2;
    int y = bid % W; bid /= W;
    int b = bid;
    int ic0 = icg * 64;
    int tid = threadIdx.x;
    for (int idx = tid; idx < 64 * W; idx += 256) {
        int i = idx / W, x = idx % W;
        tile[i][x] = in[(((size_t)(b * C_ + ic0 + i)) * W + y) * W + x];
    }
    __syncthreads();
    for (int idx = tid; idx < 64 * W; idx += 256) {
        int x = idx >> 6, i = idx & 63;
        outp[(((size_t)(b * PW + y + 1)) * PW + x + 1) * 256 + ic0 + i] =
            __float2bfloat16(tile[i][x]);
    }
}

// ---------------- weights (oc,ic,3,3) -> [tap][oc][ic] bf16 ----------------
__global__ __launch_bounds__(256)
void weight_reorg(const float* __restrict__ w, __hip_bfloat16* __restrict__ wr)
{
    int idx = blockIdx.x * 256 + threadIdx.x;   // oc*256+ic
    const float* src = w + (size_t)idx * 9;
    #pragma unroll
    for (int t = 0; t < 9; ++t)
        wr[(size_t)t * 65536 + idx] = __float2bfloat16(src[t]);
}

// ---------------- conv as implicit GEMM, MFMA bf16 ----------------
// D[oc][px] = sum_tap sum_ic Wr[tap][oc][ic] * SPc[b][y+dy][x+dx][ic]  (+bias)
template<int W>   // W=64 (s) or W=16 (t); NPIX=W*W
__global__ __launch_bounds__(256)
void conv_mfma(const __hip_bfloat16* __restrict__ SPc, const __hip_bfloat16* __restrict__ Wr,
               const float* __restrict__ bias, float* __restrict__ out)
{
    constexpr int PW = W + 2;
    constexpr int NPIX = W * W;
    constexpr int NT = NPIX / 128;
    __shared__ __hip_bfloat16 A_lds[128 * 32];
    __shared__ __hip_bfloat16 B_lds[128 * 32];

    int bid = blockIdx.x;
    int nt = bid % NT; bid /= NT;
    int mt = bid & 1;  bid >>= 1;
    int b  = bid;
    int tid = threadIdx.x;
    int lane = tid & 63;
    int wv = tid >> 6, wm = wv >> 1, wn = wv & 1;
    int oc0 = mt * 128, p0 = nt * 128;

    f32x4 acc[4][4];
    #pragma unroll
    for (int i = 0; i < 4; ++i)
        #pragma unroll
        for (int j = 0; j < 4; ++j)
            #pragma unroll
            for (int r = 0; r < 4; ++r) acc[i][j][r] = 0.f;

    const bf16x8* Af = reinterpret_cast<const bf16x8*>(A_lds);
    const bf16x8* Bf = reinterpret_cast<const bf16x8*>(B_lds);
    int colb = lane >> 4;            // frag slot 0..3 within 32-k row
    int rA = lane & 15;

    for (int kc = 0; kc < 72; ++kc) {
        int tap = kc >> 3, icc = kc & 7;
        int ic0 = icc * 32;
        int dy = tap / 3, dx = tap - dy * 3;
        __syncthreads();
        #pragma unroll
        for (int it = 0; it < 2; ++it) {
            int sIdx = tid + it * 256;
            int row = sIdx >> 2, seg = sIdx & 3;
            const __hip_bfloat16* srcA =
                Wr + ((size_t)(tap * 256 + oc0 + row)) * 256 + ic0 + seg * 8;
            gload_lds16(srcA, &A_lds[sIdx * 8]);
            int p = p0 + row;
            int y = p / W, x = p % W;
            const __hip_bfloat16* srcB =
                SPc + (((size_t)(b * PW + y + dy)) * PW + x + dx) * 256 + ic0 + seg * 8;
            gload_lds16(srcB, &B_lds[sIdx * 8]);
        }
        asm volatile("s_waitcnt vmcnt(0)" ::: "memory");
        __syncthreads();

        bf16x8 a[4], bb[4];
        #pragma unroll
        for (int mi = 0; mi < 4; ++mi)
            a[mi] = Af[(wm * 64 + mi * 16 + rA) * 4 + colb];
        #pragma unroll
        for (int ni = 0; ni < 4; ++ni)
            bb[ni] = Bf[(wn * 64 + ni * 16 + rA) * 4 + colb];
        #pragma unroll
        for (int mi = 0; mi < 4; ++mi)
            #pragma unroll
            for (int ni = 0; ni < 4; ++ni)
                acc[mi][ni] = __builtin_amdgcn_mfma_f32_16x16x32_bf16(
                    a[mi], bb[ni], acc[mi][ni], 0, 0, 0);
    }

    // epilogue: +bias, store NCHW fp32
    #pragma unroll
    for (int mi = 0; mi < 4; ++mi) {
        int ocb = oc0 + wm * 64 + mi * 16 + (lane >> 4) * 4;
        #pragma unroll
        for (int r = 0; r < 4; ++r) {
            int oc = ocb + r;
            float bv = bias[oc];
            float* orow = out + ((size_t)(b * C_ + oc)) * NPIX;
            #pragma unroll
            for (int ni = 0; ni < 4; ++ni) {
                int px = p0 + wn * 64 + ni * 16 + (lane & 15);
                orow[px] = acc[mi][ni][r] + bv;
            }
        }
    }
}

// ---------------- block reduce helper ----------------
__device__ inline void blk_reduce2(float& a, float& q, int tid) {
    #pragma unroll
    for (int off = 32; off > 0; off >>= 1) {
        a += __shfl_down(a, off);
        q += __shfl_down(q, off);
    }
    __shared__ float ra[4], rq[4];
    if ((tid & 63) == 0) { ra[tid >> 6] = a; rq[tid >> 6] = q; }
    __syncthreads();
    if (tid == 0) { a = ra[0] + ra[1] + ra[2] + ra[3]; q = rq[0] + rq[1] + rq[2] + rq[3]; }
}

// ---------------- per-channel sum/sumsq over (b, pixels) ----------------
__global__ __launch_bounds__(256)
void chan_stats(const float* __restrict__ x, float* __restrict__ csum, float* __restrict__ csq,
                int npix, int nb_per_blk, int nsplit)
{
    int c = blockIdx.x / nsplit, sp = blockIdx.x % nsplit;
    int tid = threadIdx.x;
    float s = 0.f, q = 0.f;
    for (int bb = 0; bb < nb_per_blk; ++bb) {
        int b = sp * nb_per_blk + bb;
        const float4* p = reinterpret_cast<const float4*>(x + ((size_t)(b * C_ + c)) * npix);
        for (int i = tid; i < npix / 4; i += 256) {
            float4 v = p[i];
            s += v.x + v.y + v.z + v.w;
            q += v.x * v.x + v.y * v.y + v.z * v.z + v.w * v.w;
        }
    }
    blk_reduce2(s, q, tid);
    if (tid == 0) { atomicAdd(&csum[c], s); atomicAdd(&csq[c], q); }
}

// ---------------- BN normalize in place ----------------
__global__ __launch_bounds__(256)
void bn_norm(float* __restrict__ x, const float* __restrict__ csum,
             const float* __restrict__ csq, const float* __restrict__ g,
             const float* __restrict__ be, int HW, int total4, float inv_cnt)
{
    int i = blockIdx.x * 256 + threadIdx.x;
    if (i >= total4) return;
    int c = ((i * 4) / HW) % C_;
    float m = csum[c] * inv_cnt;
    float v = csq[c] * inv_cnt - m * m;
    float sc = rsqrtf(v + EPSV) * g[c];
    float sh = be[c] - m * sc;
    float4 val = reinterpret_cast<float4*>(x)[i];
    val.x = val.x * sc + sh;
    val.y = val.y * sc + sh;
    val.z = val.z * sc + sh;
    val.w = val.w * sc + sh;
    reinterpret_cast<float4*>(x)[i] = val;
}

// ---------------- channel-summed planes of normalized s ----------------
__global__ __launch_bounds__(256)
void zplane_kernel(const float* __restrict__ s1, float* __restrict__ z, float* __restrict__ z2)
{
    int i = blockIdx.x * 256 + threadIdx.x;
    int b = i >> 12, p = i & 4095;
    const float* base = s1 + (size_t)b * C_ * 4096 + p;
    float s = 0.f, q = 0.f;
    for (int c = 0; c < C_; ++c) { float v = base[(size_t)c * 4096]; s += v; q += v * v; }
    z[i] = s; z2[i] = q;
}

// ---------------- template stats ----------------
__global__ __launch_bounds__(256)
void tstat_kernel(const float* __restrict__ t2, float* __restrict__ tmean, float* __restrict__ ttstd)
{
    int b = blockIdx.x, tid = threadIdx.x;
    const float* p = t2 + (size_t)b * NTOT;
    float s = 0.f, q = 0.f;
    for (int i = tid; i < NTOT; i += 256) { float v = p[i]; s += v; q += v * v; }
    blk_reduce2(s, q, tid);
    if (tid == 0) {
        float m = s / (float)NTOT;
        tmean[b] = m;
        ttstd[b] = sqrtf(fmaxf(q - (float)NTOT * m * m, 0.f) / (float)(NTOT - 1));
    }
}

// ---------------- raw cross-correlation partials ----------------
__global__ __launch_bounds__(256)
void cross_kernel(const float* __restrict__ s1, const float* __restrict__ t2,
                  float* __restrict__ cpart)
{
    __shared__ float spl[4096];
    __shared__ float tpl[256];
    int g = blockIdx.x & (GROUPS - 1);
    int b = blockIdx.x / GROUPS;
    int tid = threadIdx.x;

    float acc[10];
    #pragma unroll
    for (int k = 0; k < 10; ++k) acc[k] = 0.f;
    int io[10], jo[10];
    #pragma unroll
    for (int k = 0; k < 10; ++k) {
        int o = tid + k * 256;
        if (o >= OHW_) o = 0;
        io[k] = o / 49; jo[k] = o % 49;
    }

    for (int cc = 0; cc < CPERG; ++cc) {
        int c = g * CPERG + cc;
        __syncthreads();
        const float4* sp4 = reinterpret_cast<const float4*>(s1 + ((size_t)(b * C_ + c)) * 4096);
        float4* dst4 = reinterpret_cast<float4*>(spl);
        #pragma unroll
        for (int k = 0; k < 4; ++k) dst4[tid + k * 256] = sp4[tid + k * 256];
        tpl[tid] = t2[((size_t)(b * C_ + c)) * 256 + tid];
        __syncthreads();
        #pragma unroll 2
        for (int ty_ = 0; ty_ < 16; ++ty_) {
            float tr[16];
            #pragma unroll
            for (int tx_ = 0; tx_ < 16; ++tx_) tr[tx_] = tpl[ty_ * 16 + tx_];
            #pragma unroll
            for (int k = 0; k < 10; ++k) {
                const float* srow = &spl[(io[k] + ty_) * 64 + jo[k]];
                float a = acc[k];
                #pragma unroll
                for (int tx_ = 0; tx_ < 16; ++tx_) a += tr[tx_] * srow[tx_];
                acc[k] = a;
            }
        }
    }
    float* dst = cpart + ((size_t)(g * B_ + b)) * OHW_;
    #pragma unroll
    for (int k = 0; k < 9; ++k) dst[tid + k * 256] = acc[k];
    if (tid < OHW_ - 9 * 256) dst[tid + 9 * 256] = acc[9];
}

// ---------------- NCC assembly + global stats ----------------
__global__ __launch_bounds__(256)
void ncc_kernel(const float* __restrict__ cpart, const float* __restrict__ z,
                const float* __restrict__ z2, const float* __restrict__ tmean,
                const float* __restrict__ ttstd, float* __restrict__ ncc,
                float* __restrict__ s3)
{
    int idx = blockIdx.x * 256 + threadIdx.x;
    float val = 0.f;
    if (idx < B_ * OHW_) {
        int b = idx / OHW_, r = idx - b * OHW_;
        int i = r / 49, j = r - i * 49;
        float cr = 0.f;
        #pragma unroll 4
        for (int g = 0; g < GROUPS; ++g) cr += cpart[((size_t)(g * B_ + b)) * OHW_ + r];
        const float* zb  = z  + b * 4096;
        const float* z2b = z2 + b * 4096;
        float wsum = 0.f, wq = 0.f;
        for (int ty_ = 0; ty_ < 16; ++ty_) {
            const float* zr  = zb  + (i + ty_) * 64 + j;
            const float* z2r = z2b + (i + ty_) * 64 + j;
            #pragma unroll
            for (int tx_ = 0; tx_ < 16; ++tx_) { wsum += zr[tx_]; wq += z2r[tx_]; }
        }
        float crosst = cr - tmean[b] * wsum;
        float ssvar = fmaxf(wq - wsum * wsum * (1.f / 65536.f), 0.f) * (1.f / 65535.f);
        float ssstd = sqrtf(ssvar);
        val = crosst / (65536.f * ttstd[b] * ssstd);
        ncc[idx] = val;
    }
    float s = val, q = val * val;
    blk_reduce2(s, q, threadIdx.x);
    if (threadIdx.x == 0) { atomicAdd(&s3[0], s); atomicAdd(&s3[1], q); }
}

// ---------------- conv3+BN3+relu+conv4 ----------------
__global__ __launch_bounds__(256)
void final_kernel(const float* __restrict__ ncc, const float* __restrict__ s3,
                  const float* __restrict__ w3, const float* __restrict__ b3,
                  const float* __restrict__ g3, const float* __restrict__ be3,
                  const float* __restrict__ w4, const float* __restrict__ b4,
                  float* __restrict__ out)
{
    int idx = blockIdx.x * 256 + threadIdx.x;
    if (idx >= B_ * OHW_) return;
    constexpr float M = (float)(B_ * OHW_);
    float mn = s3[0] / M;
    float vn = s3[1] / M - mn * mn;
    float W3 = w3[0], B3 = b3[0];
    float my = W3 * mn + B3;
    float vy = W3 * W3 * vn;
    float sc = rsqrtf(vy + EPSV) * g3[0];
    float y = (W3 * ncc[idx] + B3 - my) * sc + be3[0];
    float h = fmaxf(y, 0.f);
    int b = idx / OHW_, r = idx - b * OHW_;
    out[((size_t)(b * 2 + 0)) * OHW_ + r] = h * w4[0] + b4[0];
    out[((size_t)(b * 2 + 1)) * OHW_ + r] = h * w4[1] + b4[1];
}

extern "C" void kernel_launch(void* const* d_in, const int* in_sizes, int n_in,
                              void* d_out, int out_size, void* d_ws, size_t ws_size,
                              hipStream_t stream)
{
    const float* s   = (const float*)d_in[0];
    const float* t   = (const float*)d_in[1];
    const float* w1  = (const float*)d_in[2];
    const float* b1  = (const float*)d_in[3];
    const float* g1  = (const float*)d_in[4];
    const float* be1 = (const float*)d_in[5];
    const float* w2  = (const float*)d_in[6];
    const float* b2  = (const float*)d_in[7];
    const float* g2  = (const float*)d_in[8];
    const float* be2 = (const float*)d_in[9];
    const float* w3  = (const float*)d_in[10];
    const float* b3  = (const float*)d_in[11];
    const float* g3  = (const float*)d_in[12];
    const float* be3 = (const float*)d_in[13];
    const float* w4  = (const float*)d_in[14];
    const float* b4  = (const float*)d_in[15];

    float* ws = (float*)d_ws;
    float* S1 = ws + OFF_S1;
    float* T2 = ws + OFF_T2;
    float* ST = ws + OFF_ST;
    float* CHS1 = ST + 0;
    float* CHQ1 = ST + 256;
    float* CHS2 = ST + 512;
    float* CHQ2 = ST + 768;
    float* S3   = ST + 1024;   // [2]
    float* TM   = ST + 1040;
    float* TSD  = ST + 1056;

    char* Cb = (char*)(ws + OFF_C);
    __hip_bfloat16* SPc = (__hip_bfloat16*)Cb;
    __hip_bfloat16* TPc = (__hip_bfloat16*)(Cb + SPC_BYTES);
    __hip_bfloat16* Wr1 = (__hip_bfloat16*)(Cb + SPC_BYTES + TPC_BYTES);
    __hip_bfloat16* Wr2 = (__hip_bfloat16*)(Cb + SPC_BYTES + TPC_BYTES + WR_BYTES);
    // overlay (alive only after convs are done)
    float* Z  = (float*)Cb + ZOFF;
    float* Z2 = (float*)Cb + Z2OFF;
    float* CP = (float*)Cb + CPOFF;
    float* NC = (float*)Cb + NCOFF;

    hipMemsetAsync(ST, 0, 1026 * sizeof(float), stream);
    hipMemsetAsync(Cb, 0, SPC_BYTES + TPC_BYTES, stream);

    pad_transpose<64><<<dim3(16 * 64 * 4), dim3(256), 0, stream>>>(s, SPc);
    pad_transpose<16><<<dim3(16 * 16 * 4), dim3(256), 0, stream>>>(t, TPc);
    weight_reorg<<<dim3(256), dim3(256), 0, stream>>>(w1, Wr1);
    weight_reorg<<<dim3(256), dim3(256), 0, stream>>>(w2, Wr2);

    conv_mfma<64><<<dim3(16 * 2 * 32), dim3(256), 0, stream>>>(SPc, Wr1, b1, S1);
    conv_mfma<16><<<dim3(16 * 2 * 2),  dim3(256), 0, stream>>>(TPc, Wr2, b2, T2);

    chan_stats<<<dim3(256 * 16), dim3(256), 0, stream>>>(S1, CHS1, CHQ1, 4096, 1, 16);
    chan_stats<<<dim3(256),      dim3(256), 0, stream>>>(T2, CHS2, CHQ2, 256, 16, 1);
    bn_norm<<<dim3(16384), dim3(256), 0, stream>>>(S1, CHS1, CHQ1, g1, be1, 4096, 4194304, 1.f / 65536.f);
    bn_norm<<<dim3(1024),  dim3(256), 0, stream>>>(T2, CHS2, CHQ2, g2, be2, 256, 262144, 1.f / 4096.f);

    zplane_kernel<<<dim3(256), dim3(256), 0, stream>>>(S1, Z, Z2);
    tstat_kernel<<<dim3(16), dim3(256), 0, stream>>>(T2, TM, TSD);
    cross_kernel<<<dim3(16 * GROUPS), dim3(256), 0, stream>>>(S1, T2, CP);
    ncc_kernel<<<dim3(151), dim3(256), 0, stream>>>(CP, Z, Z2, TM, TSD, NC, S3);
    final_kernel<<<dim3(151), dim3(256), 0, stream>>>(NC, S3, w3, b3, g3, be3, w4, b4, (float*)d_out);
}

// Round 3
// 488.562 us; speedup vs baseline: 4.4133x; 1.2541x over previous
//
#include <hip/hip_runtime.h>
#include <hip/hip_bf16.h>

#define EPSV 1e-5f

constexpr int B_ = 16, C_ = 256;
constexpr int OHW_ = 49 * 49;          // 2401
constexpr int NTOT = 256 * 16 * 16;    // 65536
constexpr int GROUPS = 32, CPERG = 8;

typedef short bf16x8 __attribute__((ext_vector_type(8)));
typedef float f32x4 __attribute__((ext_vector_type(4)));

// ---------------- workspace layout (float offsets) ----------------
constexpr size_t OFF_S1 = 0;                               // raw conv1 out, 16*256*4096 f32
constexpr size_t SZ_S1  = (size_t)16 * 256 * 4096;
constexpr size_t OFF_T2 = OFF_S1 + SZ_S1;                  // conv2 out (bn'd in place), 16*256*256
constexpr size_t SZ_T2  = (size_t)16 * 256 * 256;
constexpr size_t OFF_ST = OFF_T2 + SZ_T2;                  // stats block
constexpr size_t OFF_C  = OFF_ST + 2048;                   // overlaid big region
// region C: bf16 staging (alive only through convs)
constexpr size_t SPC_BYTES = (size_t)16 * 66 * 66 * 256 * 2;
constexpr size_t TPC_BYTES = (size_t)16 * 18 * 18 * 256 * 2;
constexpr size_t WR_BYTES  = (size_t)9 * 256 * 256 * 2;
// region C overlay (alive after convs), float offsets within region C
constexpr size_t ZOFF  = 0;                                // [2][16][4096]: z then z2
constexpr size_t CPOFF = 131072;                           // 32*16*2401
constexpr size_t NCOFF = CPOFF + (size_t)GROUPS * 16 * OHW_;
constexpr size_t SATOFF = NCOFF + (size_t)16 * OHW_;       // [2][16][65*65]

// ---------------- async global->LDS 16B ----------------
__device__ __forceinline__ void gload_lds16(const void* g, void* l) {
    __builtin_amdgcn_global_load_lds((const __attribute__((address_space(1))) unsigned int*)g,
                                     (__attribute__((address_space(3))) unsigned int*)l,
                                     16, 0, 0);
}

// ---------------- pad + NCHW->NHWC + bf16, borders written here ----------------
template<int W>   // out [b][W+2][W+2][256]
__global__ __launch_bounds__(256)
void pad_transpose(const float* __restrict__ in, __hip_bfloat16* __restrict__ outp)
{
    constexpr int PW = W + 2;
    __shared__ float tile[64][W + 1];
    int bid = blockIdx.x;
    int icg = bid & 3; bid >>= 2;
    int yp = bid % PW; bid /= PW;
    int b = bid;
    int ic0 = icg * 64;
    int tid = threadIdx.x;
    bool interior = (yp >= 1 && yp <= W);
    if (interior) {
        int y = yp - 1;
        for (int idx = tid; idx < 64 * W; idx += 256) {
            int i = idx / W, x = idx % W;
            tile[i][x] = in[(((size_t)(b * C_ + ic0 + i)) * W + y) * W + x];
        }
    }
    __syncthreads();
    for (int idx = tid; idx < PW * 16; idx += 256) {
        int xp = idx >> 4, i4 = idx & 15;
        ushort4 v = make_ushort4(0, 0, 0, 0);
        if (interior && xp >= 1 && xp <= W) {
            #pragma unroll
            for (int k = 0; k < 4; ++k) {
                __hip_bfloat16 h = __float2bfloat16(tile[i4 * 4 + k][xp - 1]);
                reinterpret_cast<unsigned short*>(&v)[k] = *reinterpret_cast<unsigned short*>(&h);
            }
        }
        *reinterpret_cast<ushort4*>(&outp[(((size_t)(b * PW) + yp) * PW + xp) * 256 + ic0 + i4 * 4]) = v;
    }
}

// ---------------- weights (oc,ic,3,3) -> [tap][oc][ic] bf16 ----------------
__global__ __launch_bounds__(256)
void weight_reorg(const float* __restrict__ w, __hip_bfloat16* __restrict__ wr)
{
    int idx = blockIdx.x * 256 + threadIdx.x;
    const float* src = w + (size_t)idx * 9;
    #pragma unroll
    for (int t = 0; t < 9; ++t)
        wr[(size_t)t * 65536 + idx] = __float2bfloat16(src[t]);
}

// ---------------- conv implicit GEMM MFMA + fused channel stats ----------------
template<int W>
__global__ __launch_bounds__(256)
void conv_mfma(const __hip_bfloat16* __restrict__ SPc, const __hip_bfloat16* __restrict__ Wr,
               const float* __restrict__ bias, float* __restrict__ out,
               float* __restrict__ csum, float* __restrict__ csq)
{
    constexpr int PW = W + 2;
    constexpr int NPIX = W * W;
    constexpr int NT = NPIX / 128;
    __shared__ __hip_bfloat16 A_lds[128 * 32];
    __shared__ __hip_bfloat16 B_lds[128 * 32];

    int bid = blockIdx.x;
    int nt = bid % NT; bid /= NT;
    int mt = bid & 1;  bid >>= 1;
    int b  = bid;
    int tid = threadIdx.x;
    int lane = tid & 63;
    int wv = tid >> 6, wm = wv >> 1, wn = wv & 1;
    int oc0 = mt * 128, p0 = nt * 128;

    f32x4 acc[4][4];
    #pragma unroll
    for (int i = 0; i < 4; ++i)
        #pragma unroll
        for (int j = 0; j < 4; ++j)
            #pragma unroll
            for (int r = 0; r < 4; ++r) acc[i][j][r] = 0.f;

    const bf16x8* Af = reinterpret_cast<const bf16x8*>(A_lds);
    const bf16x8* Bf = reinterpret_cast<const bf16x8*>(B_lds);
    int colb = lane >> 4;
    int rA = lane & 15;

    for (int kc = 0; kc < 72; ++kc) {
        int tap = kc >> 3, icc = kc & 7;
        int ic0 = icc * 32;
        int dy = tap / 3, dx = tap - dy * 3;
        __syncthreads();
        #pragma unroll
        for (int it = 0; it < 2; ++it) {
            int sIdx = tid + it * 256;
            int row = sIdx >> 2, seg = sIdx & 3;
            const __hip_bfloat16* srcA =
                Wr + ((size_t)(tap * 256 + oc0 + row)) * 256 + ic0 + seg * 8;
            gload_lds16(srcA, &A_lds[sIdx * 8]);
            int p = p0 + row;
            int y = p / W, x = p % W;
            const __hip_bfloat16* srcB =
                SPc + (((size_t)(b * PW + y + dy)) * PW + x + dx) * 256 + ic0 + seg * 8;
            gload_lds16(srcB, &B_lds[sIdx * 8]);
        }
        asm volatile("s_waitcnt vmcnt(0)" ::: "memory");
        __syncthreads();

        bf16x8 a[4], bb[4];
        #pragma unroll
        for (int mi = 0; mi < 4; ++mi)
            a[mi] = Af[(wm * 64 + mi * 16 + rA) * 4 + colb];
        #pragma unroll
        for (int ni = 0; ni < 4; ++ni)
            bb[ni] = Bf[(wn * 64 + ni * 16 + rA) * 4 + colb];
        #pragma unroll
        for (int mi = 0; mi < 4; ++mi)
            #pragma unroll
            for (int ni = 0; ni < 4; ++ni)
                acc[mi][ni] = __builtin_amdgcn_mfma_f32_16x16x32_bf16(
                    a[mi], bb[ni], acc[mi][ni], 0, 0, 0);
    }

    #pragma unroll
    for (int mi = 0; mi < 4; ++mi) {
        int ocb = oc0 + wm * 64 + mi * 16 + (lane >> 4) * 4;
        #pragma unroll
        for (int r = 0; r < 4; ++r) {
            int oc = ocb + r;
            float bv = bias[oc];
            float* orow = out + ((size_t)(b * C_ + oc)) * NPIX;
            float s_oc = 0.f, q_oc = 0.f;
            #pragma unroll
            for (int ni = 0; ni < 4; ++ni) {
                int px = p0 + wn * 64 + ni * 16 + (lane & 15);
                float v = acc[mi][ni][r] + bv;
                orow[px] = v;
                s_oc += v; q_oc += v * v;
            }
            #pragma unroll
            for (int m_ = 1; m_ < 16; m_ <<= 1) {
                s_oc += __shfl_xor(s_oc, m_);
                q_oc += __shfl_xor(q_oc, m_);
            }
            if ((lane & 15) == 0) {
                atomicAdd(&csum[oc], s_oc);
                atomicAdd(&csq[oc], q_oc);
            }
        }
    }
}

// ---------------- block reduce helper ----------------
__device__ inline void blk_reduce2(float& a, float& q, int tid) {
    #pragma unroll
    for (int off = 32; off > 0; off >>= 1) {
        a += __shfl_down(a, off);
        q += __shfl_down(q, off);
    }
    __shared__ float ra[4], rq[4];
    if ((tid & 63) == 0) { ra[tid >> 6] = a; rq[tid >> 6] = q; }
    __syncthreads();
    if (tid == 0) { a = ra[0] + ra[1] + ra[2] + ra[3]; q = rq[0] + rq[1] + rq[2] + rq[3]; }
}

// ---------------- BN normalize in place (T2 only) ----------------
__global__ __launch_bounds__(256)
void bn_norm(float* __restrict__ x, const float* __restrict__ csum,
             const float* __restrict__ csq, const float* __restrict__ g,
             const float* __restrict__ be, int HW, int total4, float inv_cnt)
{
    int i = blockIdx.x * 256 + threadIdx.x;
    if (i >= total4) return;
    int c = ((i * 4) / HW) % C_;
    float m = csum[c] * inv_cnt;
    float v = csq[c] * inv_cnt - m * m;
    float sc = rsqrtf(v + EPSV) * g[c];
    float sh = be[c] - m * sc;
    float4 val = reinterpret_cast<float4*>(x)[i];
    val.x = val.x * sc + sh;
    val.y = val.y * sc + sh;
    val.z = val.z * sc + sh;
    val.w = val.w * sc + sh;
    reinterpret_cast<float4*>(x)[i] = val;
}

// ---------------- z planes with fused BN1 affine ----------------
__global__ __launch_bounds__(256)
void zplane_kernel(const float* __restrict__ s1, const float* __restrict__ csum,
                   const float* __restrict__ csq, const float* __restrict__ g1,
                   const float* __restrict__ be1, float* __restrict__ z)
{
    __shared__ float SC[256], SH[256];
    int tid = threadIdx.x;
    {
        float m = csum[tid] * (1.f / 65536.f);
        float v = csq[tid] * (1.f / 65536.f) - m * m;
        float sc = rsqrtf(v + EPSV) * g1[tid];
        SC[tid] = sc; SH[tid] = be1[tid] - m * sc;
    }
    __syncthreads();
    int i = blockIdx.x * 256 + tid;
    int b = i >> 12, p = i & 4095;
    const float* base = s1 + (size_t)b * (C_ * 4096) + p;
    float s = 0.f, q = 0.f;
    for (int c = 0; c < C_; ++c) {
        float val = base[(size_t)c * 4096] * SC[c] + SH[c];
        s += val; q += val * val;
    }
    z[i] = s; z[65536 + i] = q;
}

// ---------------- integral images (65x65, top/left zero) ----------------
__global__ __launch_bounds__(256)
void sat_kernel(const float* __restrict__ zin, float* __restrict__ sat)
{
    __shared__ float t[65][66];
    int pl = blockIdx.x;          // 0..31 = [2][16]
    int tid = threadIdx.x;
    const float* src = zin + (size_t)pl * 4096;
    for (int idx = tid; idx < 4096; idx += 256) {
        int y = idx >> 6, x = idx & 63;
        t[y + 1][x + 1] = src[idx];
    }
    for (int idx = tid; idx < 65; idx += 256) { t[0][idx] = 0.f; t[idx][0] = 0.f; }
    __syncthreads();
    if (tid < 64) {
        float run = 0.f;
        for (int x = 1; x <= 64; ++x) { run += t[tid + 1][x]; t[tid + 1][x] = run; }
    }
    __syncthreads();
    if (tid < 64) {
        float run = 0.f;
        for (int y = 1; y <= 64; ++y) { run += t[y][tid + 1]; t[y][tid + 1] = run; }
    }
    __syncthreads();
    float* dst = sat + (size_t)pl * 4225;
    for (int idx = tid; idx < 4225; idx += 256) {
        int r = idx / 65, c = idx % 65;
        dst[idx] = t[r][c];
    }
}

// ---------------- template stats ----------------
__global__ __launch_bounds__(256)
void tstat_kernel(const float* __restrict__ t2, float* __restrict__ tmean, float* __restrict__ ttstd)
{
    int b = blockIdx.x, tid = threadIdx.x;
    const float* p = t2 + (size_t)b * NTOT;
    float s = 0.f, q = 0.f;
    for (int i = tid; i < NTOT; i += 256) { float v = p[i]; s += v; q += v * v; }
    blk_reduce2(s, q, tid);
    if (tid == 0) {
        float m = s / (float)NTOT;
        tmean[b] = m;
        ttstd[b] = sqrtf(fmaxf(q - (float)NTOT * m * m, 0.f) / (float)(NTOT - 1));
    }
}

// ---------------- cross-correlation v3: register-blocked sliding rows ----------------
// block = (b, group of 8 channels); thread (phase=tid>>6, i=tid&63) owns output row i,
// ty-quarter `phase`. LDS plane XOR-swizzled per 4-float granule for conflict-free b128.
__global__ __launch_bounds__(256, 2)
void cross_v3(const float* __restrict__ s1, const float* __restrict__ t2,
              const float* __restrict__ csum, const float* __restrict__ csq,
              const float* __restrict__ g1, const float* __restrict__ be1,
              float* __restrict__ cpart)
{
    __shared__ float4 spl4[1024];            // 64 rows x 16 granules (swizzled)
    __shared__ float tpl[256];
    __shared__ float red[4][64][49];

    int g = blockIdx.x & (GROUPS - 1);
    int b = blockIdx.x / GROUPS;
    int tid = threadIdx.x;
    int phase = tid >> 6;
    int lane = tid & 63;
    int i = lane;
    int i_ld = i < 49 ? i : 48;

    float acc[49];
    #pragma unroll
    for (int j = 0; j < 49; ++j) acc[j] = 0.f;

    #pragma unroll 1
    for (int cc = 0; cc < CPERG; ++cc) {
        int c = g * CPERG + cc;
        float m = csum[c] * (1.f / 65536.f);
        float v = csq[c] * (1.f / 65536.f) - m * m;
        float sc = rsqrtf(v + EPSV) * g1[c];
        float sh = be1[c] - m * sc;
        __syncthreads();
        const float4* sp4 = reinterpret_cast<const float4*>(s1 + ((size_t)(b * C_ + c)) * 4096);
        #pragma unroll
        for (int k = 0; k < 4; ++k) {
            int gidx = tid + k * 256;
            float4 val = sp4[gidx];
            val.x = val.x * sc + sh; val.y = val.y * sc + sh;
            val.z = val.z * sc + sh; val.w = val.w * sc + sh;
            int row = gidx >> 4, jg = gidx & 15;
            spl4[row * 16 + (jg ^ (row & 7))] = val;
        }
        tpl[tid] = t2[((size_t)(b * C_ + c)) * 256 + tid];
        __syncthreads();
        #pragma unroll 1
        for (int tyl = 0; tyl < 4; ++tyl) {
            int ty = phase * 4 + tyl;
            int row = i_ld + ty;
            float r_[64];
            #pragma unroll
            for (int jg = 0; jg < 16; ++jg) {
                float4 v4 = spl4[row * 16 + (jg ^ (row & 7))];
                r_[jg * 4 + 0] = v4.x; r_[jg * 4 + 1] = v4.y;
                r_[jg * 4 + 2] = v4.z; r_[jg * 4 + 3] = v4.w;
            }
            float tt[16];
            const float4* tp4 = reinterpret_cast<const float4*>(&tpl[ty * 16]);
            #pragma unroll
            for (int k = 0; k < 4; ++k) {
                float4 tv = tp4[k];
                tt[k * 4 + 0] = tv.x; tt[k * 4 + 1] = tv.y;
                tt[k * 4 + 2] = tv.z; tt[k * 4 + 3] = tv.w;
            }
            #pragma unroll
            for (int tx = 0; tx < 16; ++tx)
                #pragma unroll
                for (int j = 0; j < 49; ++j)
                    acc[j] += tt[tx] * r_[j + tx];
        }
    }
    __syncthreads();
    if (i < 49) {
        #pragma unroll
        for (int j = 0; j < 49; ++j) red[phase][i][j] = acc[j];
    }
    __syncthreads();
    float* dst = cpart + ((size_t)(g * B_ + b)) * OHW_;
    for (int e = tid; e < OHW_; e += 256) {
        int ii = e / 49, jj = e - ii * 49;
        dst[e] = red[0][ii][jj] + red[1][ii][jj] + red[2][ii][jj] + red[3][ii][jj];
    }
}

// ---------------- NCC assembly via SAT + global stats ----------------
__global__ __launch_bounds__(256)
void ncc_kernel(const float* __restrict__ cpart, const float* __restrict__ sat,
                const float* __restrict__ tmean, const float* __restrict__ ttstd,
                float* __restrict__ ncc, float* __restrict__ s3)
{
    int idx = blockIdx.x * 256 + threadIdx.x;
    float val = 0.f;
    if (idx < B_ * OHW_) {
        int b = idx / OHW_, r = idx - b * OHW_;
        int i = r / 49, j = r - i * 49;
        float cr = 0.f;
        #pragma unroll 4
        for (int g = 0; g < GROUPS; ++g) cr += cpart[((size_t)(g * B_ + b)) * OHW_ + r];
        const float* sz = sat + (size_t)b * 4225;
        const float* sq = sat + (size_t)(16 + b) * 4225;
        int a00 = i * 65 + j, a01 = i * 65 + j + 16;
        int a10 = (i + 16) * 65 + j, a11 = (i + 16) * 65 + j + 16;
        float wsum = sz[a11] - sz[a01] - sz[a10] + sz[a00];
        float wq   = sq[a11] - sq[a01] - sq[a10] + sq[a00];
        float crosst = cr - tmean[b] * wsum;
        float ssvar = fmaxf(wq - wsum * wsum * (1.f / 65536.f), 0.f) * (1.f / 65535.f);
        float ssstd = sqrtf(ssvar);
        val = crosst / (65536.f * ttstd[b] * ssstd);
        ncc[idx] = val;
    }
    float s = val, q = val * val;
    blk_reduce2(s, q, threadIdx.x);
    if (threadIdx.x == 0) { atomicAdd(&s3[0], s); atomicAdd(&s3[1], q); }
}

// ---------------- conv3+BN3+relu+conv4 ----------------
__global__ __launch_bounds__(256)
void final_kernel(const float* __restrict__ ncc, const float* __restrict__ s3,
                  const float* __restrict__ w3, const float* __restrict__ b3,
                  const float* __restrict__ g3, const float* __restrict__ be3,
                  const float* __restrict__ w4, const float* __restrict__ b4,
                  float* __restrict__ out)
{
    int idx = blockIdx.x * 256 + threadIdx.x;
    if (idx >= B_ * OHW_) return;
    constexpr float M = (float)(B_ * OHW_);
    float mn = s3[0] / M;
    float vn = s3[1] / M - mn * mn;
    float W3 = w3[0], B3 = b3[0];
    float my = W3 * mn + B3;
    float vy = W3 * W3 * vn;
    float sc = rsqrtf(vy + EPSV) * g3[0];
    float y = (W3 * ncc[idx] + B3 - my) * sc + be3[0];
    float h = fmaxf(y, 0.f);
    int b = idx / OHW_, r = idx - b * OHW_;
    out[((size_t)(b * 2 + 0)) * OHW_ + r] = h * w4[0] + b4[0];
    out[((size_t)(b * 2 + 1)) * OHW_ + r] = h * w4[1] + b4[1];
}

extern "C" void kernel_launch(void* const* d_in, const int* in_sizes, int n_in,
                              void* d_out, int out_size, void* d_ws, size_t ws_size,
                              hipStream_t stream)
{
    const float* s   = (const float*)d_in[0];
    const float* t   = (const float*)d_in[1];
    const float* w1  = (const float*)d_in[2];
    const float* b1  = (const float*)d_in[3];
    const float* g1  = (const float*)d_in[4];
    const float* be1 = (const float*)d_in[5];
    const float* w2  = (const float*)d_in[6];
    const float* b2  = (const float*)d_in[7];
    const float* g2  = (const float*)d_in[8];
    const float* be2 = (const float*)d_in[9];
    const float* w3  = (const float*)d_in[10];
    const float* b3  = (const float*)d_in[11];
    const float* g3  = (const float*)d_in[12];
    const float* be3 = (const float*)d_in[13];
    const float* w4  = (const float*)d_in[14];
    const float* b4  = (const float*)d_in[15];

    float* ws = (float*)d_ws;
    float* S1 = ws + OFF_S1;
    float* T2 = ws + OFF_T2;
    float* ST = ws + OFF_ST;
    float* CHS1 = ST + 0;
    float* CHQ1 = ST + 256;
    float* CHS2 = ST + 512;
    float* CHQ2 = ST + 768;
    float* S3   = ST + 1024;   // [2]
    float* TM   = ST + 1040;
    float* TSD  = ST + 1056;

    char* Cb = (char*)(ws + OFF_C);
    __hip_bfloat16* SPc = (__hip_bfloat16*)Cb;
    __hip_bfloat16* TPc = (__hip_bfloat16*)(Cb + SPC_BYTES);
    __hip_bfloat16* Wr1 = (__hip_bfloat16*)(Cb + SPC_BYTES + TPC_BYTES);
    __hip_bfloat16* Wr2 = (__hip_bfloat16*)(Cb + SPC_BYTES + TPC_BYTES + WR_BYTES);
    float* Cf = (float*)Cb;
    float* Z   = Cf + ZOFF;     // [2][16][4096]
    float* CP  = Cf + CPOFF;
    float* NC  = Cf + NCOFF;
    float* SAT = Cf + SATOFF;   // [2][16][4225]

    hipMemsetAsync(ST, 0, 1026 * sizeof(float), stream);

    pad_transpose<64><<<dim3(16 * 66 * 4), dim3(256), 0, stream>>>(s, SPc);
    pad_transpose<16><<<dim3(16 * 18 * 4), dim3(256), 0, stream>>>(t, TPc);
    weight_reorg<<<dim3(256), dim3(256), 0, stream>>>(w1, Wr1);
    weight_reorg<<<dim3(256), dim3(256), 0, stream>>>(w2, Wr2);

    conv_mfma<64><<<dim3(16 * 2 * 32), dim3(256), 0, stream>>>(SPc, Wr1, b1, S1, CHS1, CHQ1);
    conv_mfma<16><<<dim3(16 * 2 * 2),  dim3(256), 0, stream>>>(TPc, Wr2, b2, T2, CHS2, CHQ2);

    bn_norm<<<dim3(1024), dim3(256), 0, stream>>>(T2, CHS2, CHQ2, g2, be2, 256, 262144, 1.f / 4096.f);
    tstat_kernel<<<dim3(16), dim3(256), 0, stream>>>(T2, TM, TSD);

    zplane_kernel<<<dim3(256), dim3(256), 0, stream>>>(S1, CHS1, CHQ1, g1, be1, Z);
    sat_kernel<<<dim3(32), dim3(256), 0, stream>>>(Z, SAT);

    cross_v3<<<dim3(16 * GROUPS), dim3(256), 0, stream>>>(S1, T2, CHS1, CHQ1, g1, be1, CP);
    ncc_kernel<<<dim3(151), dim3(256), 0, stream>>>(CP, SAT, TM, TSD, NC, S3);
    final_kernel<<<dim3(151), dim3(256), 0, stream>>>(NC, S3, w3, b3, g3, be3, w4, b4, (float*)d_out);
}